// Round 1
// baseline (218.537 us; speedup 1.0000x reference)
//
#include <hip/hip_runtime.h>
#include <hip/hip_bf16.h>
#include <math.h>

typedef unsigned short u16;
typedef __bf16 bf16x8 __attribute__((ext_vector_type(8)));
typedef float f32x4 __attribute__((ext_vector_type(4)));
typedef unsigned short u16x4 __attribute__((ext_vector_type(4)));

#define BB 4
#define LL 4096
#define MTOK (BB*LL)        // 16384 tokens
#define HID 1024
#define RD 1024             // retrieval dim (16 tables * 64)
#define NKV 2048            // k (1024) concat v (1024)
#define KDIM 1024
#define VOCABN 32000
#define EPSF 1e-6f

__device__ __forceinline__ float bf2f(u16 x) {
  unsigned u = ((unsigned)x) << 16;
  return __builtin_bit_cast(float, u);
}
__device__ __forceinline__ u16 f2bf(float f) {
  unsigned u = __builtin_bit_cast(unsigned, f);
  u += 0x7FFFu + ((u >> 16) & 1u);   // round-to-nearest-even
  return (u16)(u >> 16);
}

// ---------------- kernel 1: convert w_k || w_v -> bf16 W[2048][1024] ----------------
__global__ __launch_bounds__(256) void k_convert_w(const float* __restrict__ wk,
                                                   const float* __restrict__ wv,
                                                   u16* __restrict__ W) {
  int i = blockIdx.x * 256 + threadIdx.x;   // group of 4 elements
  const int n4 = (NKV * KDIM) / 4;          // 524288
  if (i >= n4) return;
  const int half = n4 / 2;
  const f32x4* src = (i < half) ? (const f32x4*)wk : (const f32x4*)wv;
  int j = (i < half) ? i : i - half;
  f32x4 v = src[j];
  u16x4 o = { f2bf(v[0]), f2bf(v[1]), f2bf(v[2]), f2bf(v[3]) };
  *(u16x4*)&W[(size_t)i * 4] = o;
}

// ---------------- kernel 2: hash + gather -> bf16 memory[16384][1024] ----------------
__global__ __launch_bounds__(256) void k_gather(
    const int* __restrict__ tok, const int* __restrict__ proj,
    const int* __restrict__ m2, const int* __restrict__ m3,
    const int* __restrict__ tsz, const float* __restrict__ tables,
    int max_s, u16* __restrict__ mem) {
  int m = blockIdx.x;               // token index = b*LL + l
  int l = m & (LL - 1);
  int tid = threadIdx.x;
  int t = tid >> 4;                 // table 0..15 (order*8 + head)
  int q = tid & 15;                 // 16B quad within the 64-float row
  long long c0, c1 = 0, c2 = 0;
  {
    int tk = tok[m];
    tk = tk < 0 ? 0 : (tk > VOCABN - 1 ? VOCABN - 1 : tk);
    c0 = proj[tk];
  }
  if (l >= 1) {
    int tk = tok[m - 1];
    tk = tk < 0 ? 0 : (tk > VOCABN - 1 ? VOCABN - 1 : tk);
    c1 = proj[tk];
  }
  if (l >= 2) {
    int tk = tok[m - 2];
    tk = tk < 0 ? 0 : (tk > VOCABN - 1 ? VOCABN - 1 : tk);
    c2 = proj[tk];
  }
  int order = t >> 3, h = t & 7;
  long long mix;
  if (order == 0) {
    // ngram2: i=0 -> token l-1, i=1 -> token l
    mix = (c1 * (long long)m2[h * 2 + 0]) ^ (c0 * (long long)m2[h * 2 + 1]);
  } else {
    // ngram3: i=0 -> l-2, i=1 -> l-1, i=2 -> l
    mix = (c2 * (long long)m3[h * 3 + 0]) ^ (c1 * (long long)m3[h * 3 + 1]) ^
          (c0 * (long long)m3[h * 3 + 2]);
  }
  unsigned long long um = (unsigned long long)(mix < 0 ? -mix : mix); // mix >= 0 in practice
  unsigned long long usz = (unsigned long long)tsz[t];
  // fast 64-bit mod: um < 2^47 exactly representable in double; quotient err <= 1, fixed up.
  unsigned long long qq = (unsigned long long)((double)um / (double)usz);
  long long r = (long long)(um - qq * usz);
  if (r < 0) r += (long long)usz;
  else if (r >= (long long)usz) r -= (long long)usz;
  const f32x4* src = (const f32x4*)(tables + ((size_t)t * (size_t)max_s + (size_t)r) * 64);
  f32x4 e = src[q];
  u16x4 o = { f2bf(e[0]), f2bf(e[1]), f2bf(e[2]), f2bf(e[3]) };
  *(u16x4*)&mem[(size_t)m * RD + t * 64 + q * 4] = o;
}

// ---------------- kernel 3: bf16 MFMA GEMM C[M][2048] = A[M][1024] * W[2048][1024]^T ----------------
#define BM 128
#define BN 128
#define BK 32

__device__ __forceinline__ void gload16(const u16* g, u16* l) {
  __builtin_amdgcn_global_load_lds((__attribute__((address_space(1))) void*)(g),
                                   (__attribute__((address_space(3))) void*)(l), 16, 0, 0);
}

__global__ __launch_bounds__(256) void k_gemm(const u16* __restrict__ A,
                                              const u16* __restrict__ Bw,
                                              u16* __restrict__ C) {
  __shared__ __align__(16) u16 As[BM * BK];   // 8 KB
  __shared__ __align__(16) u16 Bs[BN * BK];   // 8 KB
  const int bx = blockIdx.x;
  const int nbn = NKV / BN;                   // 16
  const int bm = bx / nbn, bn = bx % nbn;     // consecutive blocks share the A panel
  const int tid = threadIdx.x;
  const int w = tid >> 6;                     // wave 0..3
  const int ln = tid & 63;
  const int wr = w >> 1, wc = w & 1;          // 2x2 waves -> 64x64 each
  const int lm = ln & 15, kg = ln >> 4;

  f32x4 acc[4][4];
#pragma unroll
  for (int i = 0; i < 4; ++i)
#pragma unroll
    for (int j = 0; j < 4; ++j) acc[i][j] = (f32x4){0.f, 0.f, 0.f, 0.f};

  const int rsub = ln >> 2;           // 0..15
  const int csub = (ln & 3) * 8;      // 0,8,16,24

#pragma unroll 1
  for (int kt = 0; kt < KDIM / BK; ++kt) {
    const int k0 = kt * BK;
    __syncthreads();                  // previous compute done before LDS overwrite
#pragma unroll
    for (int j = 0; j < 2; ++j) {
      const int ch = w * 2 + j;       // wave-uniform chunk id 0..7
      const int r = ch * 16 + rsub;
      const u16* ga = A + (size_t)(bm * BM + r) * KDIM + k0 + csub;
      gload16(ga, &As[ch * 512]);
      const u16* gb = Bw + (size_t)(bn * BN + r) * KDIM + k0 + csub;
      gload16(gb, &Bs[ch * 512]);
    }
    __syncthreads();

    bf16x8 af[4], bf[4];
#pragma unroll
    for (int mi = 0; mi < 4; ++mi)
      af[mi] = *(const bf16x8*)&As[(wr * 64 + mi * 16 + lm) * BK + kg * 8];
#pragma unroll
    for (int ni = 0; ni < 4; ++ni)
      bf[ni] = *(const bf16x8*)&Bs[(wc * 64 + ni * 16 + lm) * BK + kg * 8];
#pragma unroll
    for (int mi = 0; mi < 4; ++mi)
#pragma unroll
      for (int ni = 0; ni < 4; ++ni)
        acc[mi][ni] = __builtin_amdgcn_mfma_f32_16x16x32_bf16(af[mi], bf[ni], acc[mi][ni], 0, 0, 0);
  }

  // C/D layout (m89-verified): col = lane&15, row = (lane>>4)*4 + reg
#pragma unroll
  for (int mi = 0; mi < 4; ++mi) {
#pragma unroll
    for (int ni = 0; ni < 4; ++ni) {
      const int col = bn * BN + wc * 64 + ni * 16 + lm;
#pragma unroll
      for (int jj = 0; jj < 4; ++jj) {
        const int row = bm * BM + wr * 64 + mi * 16 + kg * 4 + jj;
        C[(size_t)row * NKV + col] = f2bf(acc[mi][ni][jj]);
      }
    }
  }
}

// ---------------- kernel 4: gate + v_g + rmsnorm(v_g) ----------------
__device__ __forceinline__ float block_sum(float v) {
  __shared__ float red[4];
#pragma unroll
  for (int m = 32; m >= 1; m >>= 1) v += __shfl_xor(v, m, 64);
  __syncthreads();
  if ((threadIdx.x & 63) == 0) red[threadIdx.x >> 6] = v;
  __syncthreads();
  return red[0] + red[1] + red[2] + red[3];
}

__global__ __launch_bounds__(256) void k_gate(const float* __restrict__ hidden,
                                              const u16* __restrict__ KV,
                                              const float* __restrict__ qw,
                                              const float* __restrict__ kw,
                                              const float* __restrict__ cw,
                                              float* __restrict__ vg,
                                              u16* __restrict__ hn) {
  const int m = blockIdx.x;
  const int c = threadIdx.x * 4;
  f32x4 x = *(const f32x4*)&hidden[(size_t)m * HID + c];
  float ssq = x[0]*x[0] + x[1]*x[1] + x[2]*x[2] + x[3]*x[3];
  float rq = rsqrtf(block_sum(ssq) * (1.f / 1024.f) + EPSF);

  u16x4 kr = *(const u16x4*)&KV[(size_t)m * NKV + c];
  float k0 = bf2f(kr[0]), k1 = bf2f(kr[1]), k2 = bf2f(kr[2]), k3 = bf2f(kr[3]);
  float ssk = k0*k0 + k1*k1 + k2*k2 + k3*k3;
  float rk = rsqrtf(block_sum(ssk) * (1.f / 1024.f) + EPSF);

  f32x4 qv = *(const f32x4*)&qw[c];
  f32x4 kv = *(const f32x4*)&kw[c];
  float dp = (x[0]*rq*qv[0])*(k0*rk*kv[0]) + (x[1]*rq*qv[1])*(k1*rk*kv[1]) +
             (x[2]*rq*qv[2])*(k2*rk*kv[2]) + (x[3]*rq*qv[3])*(k3*rk*kv[3]);
  float dot = block_sum(dp);
  float gate = 1.f / (1.f + expf(-dot * 0.03125f));   // scale = 1/sqrt(1024)

  u16x4 vr = *(const u16x4*)&KV[(size_t)m * NKV + 1024 + c];
  float v0 = gate * bf2f(vr[0]), v1 = gate * bf2f(vr[1]);
  float v2 = gate * bf2f(vr[2]), v3 = gate * bf2f(vr[3]);
  *(f32x4*)&vg[(size_t)m * HID + c] = (f32x4){v0, v1, v2, v3};

  float ssv = v0*v0 + v1*v1 + v2*v2 + v3*v3;
  float rv = rsqrtf(block_sum(ssv) * (1.f / 1024.f) + EPSF);
  f32x4 cwv = *(const f32x4*)&cw[c];
  u16x4 ho = { f2bf(v0*rv*cwv[0]), f2bf(v1*rv*cwv[1]), f2bf(v2*rv*cwv[2]), f2bf(v3*rv*cwv[3]) };
  *(u16x4*)&hn[(size_t)m * HID + c] = ho;
}

// ---------------- kernel 5: dilated causal conv + silu + add v_g (in place on out) ----------------
__global__ __launch_bounds__(256) void k_conv(const u16* __restrict__ hn,
                                              const float* __restrict__ convw,
                                              const float* __restrict__ convb,
                                              float* __restrict__ out) {
  const int m = blockIdx.x;
  const int b = m >> 12;              // / 4096
  const int l = m & (LL - 1);
  const int c = threadIdx.x * 4;
  float a[4];
  f32x4 cb = *(const f32x4*)&convb[c];
  a[0] = cb[0]; a[1] = cb[1]; a[2] = cb[2]; a[3] = cb[3];
  f32x4 wv[4];
#pragma unroll
  for (int i = 0; i < 4; ++i) wv[i] = *(const f32x4*)&convw[(c + i) * 4];
#pragma unroll
  for (int j = 0; j < 4; ++j) {
    int ll = l - 9 + 3 * j;
    if (ll >= 0) {
      u16x4 hv = *(const u16x4*)&hn[((size_t)b * LL + ll) * HID + c];
#pragma unroll
      for (int i = 0; i < 4; ++i) a[i] += bf2f(hv[i]) * wv[i][j];
    }
  }
  f32x4 vgv = *(const f32x4*)&out[(size_t)m * HID + c];
  f32x4 res;
#pragma unroll
  for (int i = 0; i < 4; ++i) {
    float y = a[i];
    res[i] = y / (1.f + expf(-y)) + vgv[i];
  }
  *(f32x4*)&out[(size_t)m * HID + c] = res;
}

// ---------------- launch ----------------
extern "C" void kernel_launch(void* const* d_in, const int* in_sizes, int n_in,
                              void* d_out, int out_size, void* d_ws, size_t ws_size,
                              hipStream_t stream) {
  const float* hidden   = (const float*)d_in[0];
  const int*   tok      = (const int*)d_in[1];
  const int*   proj     = (const int*)d_in[2];
  const int*   m2       = (const int*)d_in[3];
  const int*   m3       = (const int*)d_in[4];
  const int*   tsz      = (const int*)d_in[5];
  const float* tables   = (const float*)d_in[6];
  const float* wk       = (const float*)d_in[7];
  const float* wv       = (const float*)d_in[8];
  const float* qw       = (const float*)d_in[9];
  const float* kw       = (const float*)d_in[10];
  const float* cnw      = (const float*)d_in[11];
  const float* convw    = (const float*)d_in[12];
  const float* convb    = (const float*)d_in[13];
  float* out = (float*)d_out;

  const int max_s = in_sizes[6] / (2 * 8 * 64);

  char* ws = (char*)d_ws;
  u16* mem = (u16*)ws;                                     // 32 MB  bf16 memory[16384][1024]
  u16* W   = (u16*)(ws + (size_t)33554432);                //  4 MB  bf16 W[2048][1024]
  u16* KV  = (u16*)(ws + (size_t)33554432 + 4194304);      // 64 MB  bf16 kv[16384][2048]
  u16* Hn  = (u16*)(ws + (size_t)33554432 + 4194304 + 67108864); // 32 MB bf16 h[16384][1024]

  k_convert_w<<<dim3((NKV * KDIM / 4 + 255) / 256), dim3(256), 0, stream>>>(wk, wv, W);
  k_gather<<<dim3(MTOK), dim3(256), 0, stream>>>(tok, proj, m2, m3, tsz, tables, max_s, mem);
  k_gemm<<<dim3((MTOK / BM) * (NKV / BN)), dim3(256), 0, stream>>>(mem, W, KV);
  k_gate<<<dim3(MTOK), dim3(256), 0, stream>>>(hidden, KV, qw, kw, cnw, out, Hn);
  k_conv<<<dim3(MTOK), dim3(256), 0, stream>>>(Hn, convw, convb, out);
}

// Round 2
// 214.470 us; speedup vs baseline: 1.0190x; 1.0190x over previous
//
#include <hip/hip_runtime.h>
#include <hip/hip_bf16.h>
#include <math.h>

typedef unsigned short u16;
typedef __bf16 bf16x8 __attribute__((ext_vector_type(8)));
typedef float f32x4 __attribute__((ext_vector_type(4)));
typedef unsigned short u16x4 __attribute__((ext_vector_type(4)));

#define BB 4
#define LL 4096
#define MTOK (BB*LL)        // 16384 tokens
#define HID 1024
#define RD 1024             // retrieval dim (16 tables * 64)
#define NKV 2048            // k (1024) concat v (1024)
#define KDIM 1024
#define VOCABN 32000
#define EPSF 1e-6f

__device__ __forceinline__ float bf2f(u16 x) {
  unsigned u = ((unsigned)x) << 16;
  return __builtin_bit_cast(float, u);
}
__device__ __forceinline__ u16 f2bf(float f) {
  unsigned u = __builtin_bit_cast(unsigned, f);
  u += 0x7FFFu + ((u >> 16) & 1u);   // round-to-nearest-even
  return (u16)(u >> 16);
}

// ---------------- kernel 1: convert w_k || w_v -> bf16 W[2048][1024] ----------------
__global__ __launch_bounds__(256) void k_convert_w(const float* __restrict__ wk,
                                                   const float* __restrict__ wv,
                                                   u16* __restrict__ W) {
  int i = blockIdx.x * 256 + threadIdx.x;   // group of 4 elements
  const int n4 = (NKV * KDIM) / 4;          // 524288
  if (i >= n4) return;
  const int half = n4 / 2;
  const f32x4* src = (i < half) ? (const f32x4*)wk : (const f32x4*)wv;
  int j = (i < half) ? i : i - half;
  f32x4 v = src[j];
  u16x4 o = { f2bf(v[0]), f2bf(v[1]), f2bf(v[2]), f2bf(v[3]) };
  *(u16x4*)&W[(size_t)i * 4] = o;
}

// ---------------- kernel 2: hash + gather -> bf16 memory[16384][1024] ----------------
__global__ __launch_bounds__(256) void k_gather(
    const int* __restrict__ tok, const int* __restrict__ proj,
    const int* __restrict__ m2, const int* __restrict__ m3,
    const int* __restrict__ tsz, const float* __restrict__ tables,
    int max_s, u16* __restrict__ mem) {
  int m = blockIdx.x;               // token index = b*LL + l
  int l = m & (LL - 1);
  int tid = threadIdx.x;
  int t = tid >> 4;                 // table 0..15 (order*8 + head)
  int q = tid & 15;                 // 16B quad within the 64-float row
  long long c0, c1 = 0, c2 = 0;
  {
    int tk = tok[m];
    tk = tk < 0 ? 0 : (tk > VOCABN - 1 ? VOCABN - 1 : tk);
    c0 = proj[tk];
  }
  if (l >= 1) {
    int tk = tok[m - 1];
    tk = tk < 0 ? 0 : (tk > VOCABN - 1 ? VOCABN - 1 : tk);
    c1 = proj[tk];
  }
  if (l >= 2) {
    int tk = tok[m - 2];
    tk = tk < 0 ? 0 : (tk > VOCABN - 1 ? VOCABN - 1 : tk);
    c2 = proj[tk];
  }
  int order = t >> 3, h = t & 7;
  long long mix;
  if (order == 0) {
    mix = (c1 * (long long)m2[h * 2 + 0]) ^ (c0 * (long long)m2[h * 2 + 1]);
  } else {
    mix = (c2 * (long long)m3[h * 3 + 0]) ^ (c1 * (long long)m3[h * 3 + 1]) ^
          (c0 * (long long)m3[h * 3 + 2]);
  }
  unsigned long long um = (unsigned long long)(mix < 0 ? -mix : mix);
  unsigned long long usz = (unsigned long long)tsz[t];
  unsigned long long qq = (unsigned long long)((double)um / (double)usz);
  long long r = (long long)(um - qq * usz);
  if (r < 0) r += (long long)usz;
  else if (r >= (long long)usz) r -= (long long)usz;
  const f32x4* src = (const f32x4*)(tables + ((size_t)t * (size_t)max_s + (size_t)r) * 64);
  f32x4 e = src[q];
  u16x4 o = { f2bf(e[0]), f2bf(e[1]), f2bf(e[2]), f2bf(e[3]) };
  *(u16x4*)&mem[(size_t)m * RD + t * 64 + q * 4] = o;
}

// ---------------- kernel 3: 256x256 8-phase bf16 MFMA GEMM ----------------
// C[16384][2048] = A[16384][1024] * Bw[2048][1024]^T   (both K-major)
#define GBM 256
#define GBN 256
#define GBK 64
#define GNT (KDIM / GBK)     // 16 K-tiles
#define BUFB 65536           // bytes per LDS buffer (A 32K + B 32K)

__device__ __forceinline__ void gload16(const void* g, void* l) {
  __builtin_amdgcn_global_load_lds((__attribute__((address_space(1))) void*)(g),
                                   (__attribute__((address_space(3))) void*)(l), 16, 0, 0);
}
__device__ __forceinline__ int swz(int x) { return x ^ (((x >> 9) & 1) << 5); }

__global__ __launch_bounds__(512, 2) void k_gemm256(const u16* __restrict__ A,
                                                    const u16* __restrict__ Bw,
                                                    u16* __restrict__ C) {
  __shared__ __align__(16) char lds[131072];
  // XCD-bijective swizzle: 512 wgs, 8 XCDs, consecutive work ids per XCD.
  const int d = blockIdx.x;
  const int wg = (d & 7) * 64 + (d >> 3);
  const int bm = wg >> 3, bn = wg & 7;   // bn fastest: 64 wgs/XCD share full B panel (4MB = L2)
  const int tid = threadIdx.x;
  const int w = tid >> 6, lane = tid & 63;
  const int wm = w >> 2, wn = w & 3;     // 2M x 4N waves; per-wave out 128x64
  const int lm = lane & 15, kg = lane >> 4;

  // stage source offsets: linear LDS dest, pre-swizzled global source (rule #21)
  int offs[4];
#pragma unroll
  for (int j = 0; j < 4; ++j) {
    int c = w * 4 + j;
    int dlin = c * 1024 + lane * 16;     // linear byte within 32KB tile
    int s = swz(dlin);
    offs[j] = (s >> 7) * KDIM + ((s & 127) >> 1);  // u16 offset: row*K + col
  }
  const u16* Apanel = A + (size_t)bm * GBM * KDIM;
  const u16* Bpanel = Bw + (size_t)bn * GBN * KDIM;

  // fragment ds_read byte offsets (within one buffer), swizzled
  int aro[8][2], bro[4][2];
#pragma unroll
  for (int mi = 0; mi < 8; ++mi)
#pragma unroll
    for (int ks = 0; ks < 2; ++ks) {
      int lin = (wm * 128 + mi * 16 + lm) * 128 + ks * 64 + kg * 16;
      aro[mi][ks] = swz(lin);
    }
#pragma unroll
  for (int ni = 0; ni < 4; ++ni)
#pragma unroll
    for (int ks = 0; ks < 2; ++ks) {
      int lin = (wn * 64 + ni * 16 + lm) * 128 + ks * 64 + kg * 16;
      bro[ni][ks] = 32768 + swz(lin);
    }

  f32x4 acc[8][4];
#pragma unroll
  for (int i = 0; i < 8; ++i)
#pragma unroll
    for (int j = 0; j < 4; ++j) acc[i][j] = (f32x4){0.f, 0.f, 0.f, 0.f};

#define STAGE(kt, nb)                                                          \
  {                                                                            \
    _Pragma("unroll")                                                          \
    for (int j = 0; j < 4; ++j) {                                              \
      int c = w * 4 + j;                                                       \
      gload16(Apanel + offs[j] + (kt) * GBK, lds + (nb) * BUFB + c * 1024);    \
      gload16(Bpanel + offs[j] + (kt) * GBK, lds + (nb) * BUFB + 32768 + c * 1024); \
    }                                                                          \
  }

  // body of one K-tile: 4 phases, quadrant = (Mhalf, Nhalf)
#define KTILE(kt, cur)                                                         \
  {                                                                            \
    const char* buf = lds + (cur) * BUFB;                                      \
    _Pragma("unroll")                                                          \
    for (int q = 0; q < 4; ++q) {                                              \
      const int Mh = q >> 1, Nh = q & 1;                                       \
      bf16x8 af[4][2], bfr[2][2];                                              \
      _Pragma("unroll")                                                        \
      for (int i = 0; i < 4; ++i)                                              \
        _Pragma("unroll")                                                      \
        for (int ks = 0; ks < 2; ++ks)                                         \
          af[i][ks] = *(const bf16x8*)(buf + aro[Mh * 4 + i][ks]);             \
      _Pragma("unroll")                                                        \
      for (int i = 0; i < 2; ++i)                                              \
        _Pragma("unroll")                                                      \
        for (int ks = 0; ks < 2; ++ks)                                         \
          bfr[i][ks] = *(const bf16x8*)(buf + bro[Nh * 2 + i][ks]);            \
      if (q == 0 && (kt) + 1 < GNT) STAGE((kt) + 1, (cur) ^ 1);                \
      __builtin_amdgcn_s_barrier();                                            \
      asm volatile("s_waitcnt lgkmcnt(0)" ::: "memory");                       \
      __builtin_amdgcn_sched_barrier(0);                                       \
      __builtin_amdgcn_s_setprio(1);                                           \
      _Pragma("unroll")                                                        \
      for (int i = 0; i < 4; ++i)                                              \
        _Pragma("unroll")                                                      \
        for (int jn = 0; jn < 2; ++jn)                                         \
          _Pragma("unroll")                                                    \
          for (int ks = 0; ks < 2; ++ks)                                       \
            acc[Mh * 4 + i][Nh * 2 + jn] = __builtin_amdgcn_mfma_f32_16x16x32_bf16( \
                af[i][ks], bfr[jn][ks], acc[Mh * 4 + i][Nh * 2 + jn], 0, 0, 0);\
      __builtin_amdgcn_s_setprio(0);                                           \
      if (q == 3) asm volatile("s_waitcnt vmcnt(0)" ::: "memory");             \
      __builtin_amdgcn_s_barrier();                                            \
    }                                                                          \
  }

  STAGE(0, 0);
  asm volatile("s_waitcnt vmcnt(0)" ::: "memory");
  __builtin_amdgcn_s_barrier();

#pragma unroll 1
  for (int kt2 = 0; kt2 < GNT; kt2 += 2) {
    KTILE(kt2, 0);
    KTILE(kt2 + 1, 1);
  }

  // ---- epilogue: LDS transpose -> coalesced stores ----
  u16* tile = (u16*)lds;   // [256][256] bf16 = 128KB
#pragma unroll
  for (int mi = 0; mi < 8; ++mi)
#pragma unroll
    for (int ni = 0; ni < 4; ++ni)
#pragma unroll
      for (int jj = 0; jj < 4; ++jj) {
        int r = wm * 128 + mi * 16 + kg * 4 + jj;
        int ccol = wn * 64 + ni * 16 + lm;
        tile[r * 256 + ccol] = f2bf(acc[mi][ni][jj]);
      }
  __syncthreads();
#pragma unroll
  for (int it = 0; it < 16; ++it) {
    int r = it * 16 + (tid >> 5);
    int cb = (tid & 31) * 16;    // byte col within 512B row
    *(f32x4*)((char*)C + ((size_t)(bm * GBM + r) * NKV + bn * GBN) * 2 + cb) =
        *(const f32x4*)((char*)tile + r * 512 + cb);
  }
#undef STAGE
#undef KTILE
}

// ---------------- kernel 4: gate + v_g + rmsnorm(v_g) ----------------
__device__ __forceinline__ float block_sum(float v) {
  __shared__ float red[4];
#pragma unroll
  for (int m = 32; m >= 1; m >>= 1) v += __shfl_xor(v, m, 64);
  __syncthreads();
  if ((threadIdx.x & 63) == 0) red[threadIdx.x >> 6] = v;
  __syncthreads();
  return red[0] + red[1] + red[2] + red[3];
}

__global__ __launch_bounds__(256) void k_gate(const float* __restrict__ hidden,
                                              const u16* __restrict__ KV,
                                              const float* __restrict__ qw,
                                              const float* __restrict__ kw,
                                              const float* __restrict__ cw,
                                              float* __restrict__ vg,
                                              u16* __restrict__ hn) {
  const int m = blockIdx.x;
  const int c = threadIdx.x * 4;
  f32x4 x = *(const f32x4*)&hidden[(size_t)m * HID + c];
  float ssq = x[0]*x[0] + x[1]*x[1] + x[2]*x[2] + x[3]*x[3];
  float rq = rsqrtf(block_sum(ssq) * (1.f / 1024.f) + EPSF);

  u16x4 kr = *(const u16x4*)&KV[(size_t)m * NKV + c];
  float k0 = bf2f(kr[0]), k1 = bf2f(kr[1]), k2 = bf2f(kr[2]), k3 = bf2f(kr[3]);
  float ssk = k0*k0 + k1*k1 + k2*k2 + k3*k3;
  float rk = rsqrtf(block_sum(ssk) * (1.f / 1024.f) + EPSF);

  f32x4 qv = *(const f32x4*)&qw[c];
  f32x4 kv = *(const f32x4*)&kw[c];
  float dp = (x[0]*rq*qv[0])*(k0*rk*kv[0]) + (x[1]*rq*qv[1])*(k1*rk*kv[1]) +
             (x[2]*rq*qv[2])*(k2*rk*kv[2]) + (x[3]*rq*qv[3])*(k3*rk*kv[3]);
  float dot = block_sum(dp);
  float gate = 1.f / (1.f + expf(-dot * 0.03125f));   // scale = 1/sqrt(1024)

  u16x4 vr = *(const u16x4*)&KV[(size_t)m * NKV + 1024 + c];
  float v0 = gate * bf2f(vr[0]), v1 = gate * bf2f(vr[1]);
  float v2 = gate * bf2f(vr[2]), v3 = gate * bf2f(vr[3]);
  *(f32x4*)&vg[(size_t)m * HID + c] = (f32x4){v0, v1, v2, v3};

  float ssv = v0*v0 + v1*v1 + v2*v2 + v3*v3;
  float rv = rsqrtf(block_sum(ssv) * (1.f / 1024.f) + EPSF);
  f32x4 cwv = *(const f32x4*)&cw[c];
  u16x4 ho = { f2bf(v0*rv*cwv[0]), f2bf(v1*rv*cwv[1]), f2bf(v2*rv*cwv[2]), f2bf(v3*rv*cwv[3]) };
  *(u16x4*)&hn[(size_t)m * HID + c] = ho;
}

// ---------------- kernel 5: dilated causal conv + silu + add v_g ----------------
__global__ __launch_bounds__(256) void k_conv(const u16* __restrict__ hn,
                                              const float* __restrict__ convw,
                                              const float* __restrict__ convb,
                                              float* __restrict__ out) {
  const int m = blockIdx.x;
  const int b = m >> 12;
  const int l = m & (LL - 1);
  const int c = threadIdx.x * 4;
  float a[4];
  f32x4 cb = *(const f32x4*)&convb[c];
  a[0] = cb[0]; a[1] = cb[1]; a[2] = cb[2]; a[3] = cb[3];
  f32x4 wv[4];
#pragma unroll
  for (int i = 0; i < 4; ++i) wv[i] = *(const f32x4*)&convw[(c + i) * 4];
#pragma unroll
  for (int j = 0; j < 4; ++j) {
    int ll = l - 9 + 3 * j;
    if (ll >= 0) {
      u16x4 hv = *(const u16x4*)&hn[((size_t)b * LL + ll) * HID + c];
#pragma unroll
      for (int i = 0; i < 4; ++i) a[i] += bf2f(hv[i]) * wv[i][j];
    }
  }
  f32x4 vgv = *(const f32x4*)&out[(size_t)m * HID + c];
  f32x4 res;
#pragma unroll
  for (int i = 0; i < 4; ++i) {
    float y = a[i];
    res[i] = y / (1.f + expf(-y)) + vgv[i];
  }
  *(f32x4*)&out[(size_t)m * HID + c] = res;
}

// ---------------- launch ----------------
extern "C" void kernel_launch(void* const* d_in, const int* in_sizes, int n_in,
                              void* d_out, int out_size, void* d_ws, size_t ws_size,
                              hipStream_t stream) {
  const float* hidden   = (const float*)d_in[0];
  const int*   tok      = (const int*)d_in[1];
  const int*   proj     = (const int*)d_in[2];
  const int*   m2       = (const int*)d_in[3];
  const int*   m3       = (const int*)d_in[4];
  const int*   tsz      = (const int*)d_in[5];
  const float* tables   = (const float*)d_in[6];
  const float* wk       = (const float*)d_in[7];
  const float* wv       = (const float*)d_in[8];
  const float* qw       = (const float*)d_in[9];
  const float* kw       = (const float*)d_in[10];
  const float* cnw      = (const float*)d_in[11];
  const float* convw    = (const float*)d_in[12];
  const float* convb    = (const float*)d_in[13];
  float* out = (float*)d_out;

  const int max_s = in_sizes[6] / (2 * 8 * 64);

  char* ws = (char*)d_ws;
  u16* mem = (u16*)ws;                                     // 32 MB  bf16 memory[16384][1024]
  u16* W   = (u16*)(ws + (size_t)33554432);                //  4 MB  bf16 W[2048][1024]
  u16* KV  = (u16*)(ws + (size_t)33554432 + 4194304);      // 64 MB  bf16 kv[16384][2048]
  u16* Hn  = (u16*)(ws + (size_t)33554432 + 4194304 + 67108864); // 32 MB bf16 h[16384][1024]

  k_convert_w<<<dim3((NKV * KDIM / 4 + 255) / 256), dim3(256), 0, stream>>>(wk, wv, W);
  k_gather<<<dim3(MTOK), dim3(256), 0, stream>>>(tok, proj, m2, m3, tsz, tables, max_s, mem);
  k_gemm256<<<dim3((MTOK / GBM) * (NKV / GBN)), dim3(512), 0, stream>>>(mem, W, KV);
  k_gate<<<dim3(MTOK), dim3(256), 0, stream>>>(hidden, KV, qw, kw, cnw, out, Hn);
  k_conv<<<dim3(MTOK), dim3(256), 0, stream>>>(Hn, convw, convb, out);
}

// Round 3
// 182.329 us; speedup vs baseline: 1.1986x; 1.1763x over previous
//
#include <hip/hip_runtime.h>
#include <hip/hip_bf16.h>
#include <math.h>

typedef unsigned short u16;
typedef __bf16 bf16x8 __attribute__((ext_vector_type(8)));
typedef float f32x4 __attribute__((ext_vector_type(4)));
typedef unsigned short u16x4 __attribute__((ext_vector_type(4)));

#define BB 4
#define LL 4096
#define MTOK (BB*LL)
#define HID 1024
#define RD 1024
#define NKV 2048
#define KDIM 1024
#define VOCABN 32000
#define EPSF 1e-6f

__device__ __forceinline__ float bf2f(u16 x) {
  unsigned u = ((unsigned)x) << 16;
  return __builtin_bit_cast(float, u);
}
__device__ __forceinline__ u16 f2bf(float f) {
  unsigned u = __builtin_bit_cast(unsigned, f);
  u += 0x7FFFu + ((u >> 16) & 1u);
  return (u16)(u >> 16);
}

// ---------------- kernel 1: convert w_k || w_v -> bf16 W[2048][1024] ----------------
__global__ __launch_bounds__(256) void k_convert_w(const float* __restrict__ wk,
                                                   const float* __restrict__ wv,
                                                   u16* __restrict__ W) {
  int i = blockIdx.x * 256 + threadIdx.x;
  const int n4 = (NKV * KDIM) / 4;
  if (i >= n4) return;
  const int half = n4 / 2;
  const f32x4* src = (i < half) ? (const f32x4*)wk : (const f32x4*)wv;
  int j = (i < half) ? i : i - half;
  f32x4 v = src[j];
  u16x4 o = { f2bf(v[0]), f2bf(v[1]), f2bf(v[2]), f2bf(v[3]) };
  *(u16x4*)&W[(size_t)i * 4] = o;
}

// ---------------- kernel 2: hash + gather -> bf16 memory[16384][1024] ----------------
__global__ __launch_bounds__(256) void k_gather(
    const int* __restrict__ tok, const int* __restrict__ proj,
    const int* __restrict__ m2, const int* __restrict__ m3,
    const int* __restrict__ tsz, const float* __restrict__ tables,
    int max_s, u16* __restrict__ mem) {
  int m = blockIdx.x;
  int l = m & (LL - 1);
  int tid = threadIdx.x;
  int t = tid >> 4;
  int q = tid & 15;
  long long c0, c1 = 0, c2 = 0;
  {
    int tk = tok[m];
    tk = tk < 0 ? 0 : (tk > VOCABN - 1 ? VOCABN - 1 : tk);
    c0 = proj[tk];
  }
  if (l >= 1) {
    int tk = tok[m - 1];
    tk = tk < 0 ? 0 : (tk > VOCABN - 1 ? VOCABN - 1 : tk);
    c1 = proj[tk];
  }
  if (l >= 2) {
    int tk = tok[m - 2];
    tk = tk < 0 ? 0 : (tk > VOCABN - 1 ? VOCABN - 1 : tk);
    c2 = proj[tk];
  }
  int order = t >> 3, h = t & 7;
  long long mix;
  if (order == 0) {
    mix = (c1 * (long long)m2[h * 2 + 0]) ^ (c0 * (long long)m2[h * 2 + 1]);
  } else {
    mix = (c2 * (long long)m3[h * 3 + 0]) ^ (c1 * (long long)m3[h * 3 + 1]) ^
          (c0 * (long long)m3[h * 3 + 2]);
  }
  unsigned long long um = (unsigned long long)(mix < 0 ? -mix : mix);
  unsigned long long usz = (unsigned long long)tsz[t];
  unsigned long long qq = (unsigned long long)((double)um / (double)usz);
  long long r = (long long)(um - qq * usz);
  if (r < 0) r += (long long)usz;
  else if (r >= (long long)usz) r -= (long long)usz;
  const f32x4* src = (const f32x4*)(tables + ((size_t)t * (size_t)max_s + (size_t)r) * 64);
  f32x4 e = src[q];
  u16x4 o = { f2bf(e[0]), f2bf(e[1]), f2bf(e[2]), f2bf(e[3]) };
  *(u16x4*)&mem[(size_t)m * RD + t * 64 + q * 4] = o;
}

// ---------------- kernel 3: 256x256 GEMM, BK=32, 4-buffer 2-deep pipeline ----------------
// C[16384][2048] = A[16384][1024] * Bw[2048][1024]^T
#define GBK2 32
#define NT2 32          // KDIM / GBK2
#define BUF2 32768      // A 16KB + B 16KB per buffer; 4 buffers = 128KB

__device__ __forceinline__ void gload16(const void* g, void* l) {
  __builtin_amdgcn_global_load_lds((__attribute__((address_space(1))) void*)(g),
                                   (__attribute__((address_space(3))) void*)(l), 16, 0, 0);
}
// involution within a 64B row-pair group: XOR 16B-line index (bits 4-5) with row bits (bits 6-7)
__device__ __forceinline__ int swz32(int x) { return x ^ (((x >> 6) & 3) << 4); }

__global__ __launch_bounds__(512, 2) void k_gemm(const u16* __restrict__ A,
                                                 const u16* __restrict__ Bw,
                                                 u16* __restrict__ C) {
  __shared__ __align__(16) char lds[131072];
  const int d = blockIdx.x;
  const int wg = (d & 7) * 64 + (d >> 3);     // XCD-bijective (512 % 8 == 0)
  const int bm = wg >> 3, bn = wg & 7;        // bn fastest within an XCD
  const int tid = threadIdx.x;
  const int w = tid >> 6, lane = tid & 63;
  const int wm = w >> 2, wn = w & 3;          // 2M x 4N waves, per-wave out 128x64
  const int lm = lane & 15, kg = lane >> 4;

  // ---- staging addressing: linear LDS dest, pre-swizzled global source ----
  // chunk ca covers 1KB of a 16KB area: rows ca*16 .. ca*16+15 (64B per row)
  const int ca0 = w * 2, ca1 = w * 2 + 1;
  const int row0 = ca0 * 16 + (lane >> 2);
  const int row1 = ca1 * 16 + (lane >> 2);
  const int off0 = row0 * KDIM + (((lane & 3) ^ (row0 & 3)) << 3);  // u16 elems
  const int off1 = row1 * KDIM + (((lane & 3) ^ (row1 & 3)) << 3);
  const int dstA0 = ca0 * 1024 + lane * 16;   // byte offsets within a buffer
  const int dstA1 = ca1 * 1024 + lane * 16;
  const u16* Ap = A + (size_t)bm * 256 * KDIM;
  const u16* Bp = Bw + (size_t)bn * 256 * KDIM;

  // ---- fragment ds_read offsets (physical, swizzled) ----
  int aro[8], bro[4];
#pragma unroll
  for (int mi = 0; mi < 8; ++mi)
    aro[mi] = swz32((wm * 128 + mi * 16 + lm) * 64 + kg * 16);
#pragma unroll
  for (int ni = 0; ni < 4; ++ni)
    bro[ni] = 16384 + swz32((wn * 64 + ni * 16 + lm) * 64 + kg * 16);

  f32x4 acc[8][4];
#pragma unroll
  for (int i = 0; i < 8; ++i)
#pragma unroll
    for (int j = 0; j < 4; ++j) acc[i][j] = (f32x4){0.f, 0.f, 0.f, 0.f};

#define STG(kt, bb)                                                        \
  {                                                                        \
    char* bbase = lds + (bb) * BUF2;                                       \
    gload16(Ap + off0 + (kt) * GBK2, bbase + dstA0);                       \
    gload16(Bp + off0 + (kt) * GBK2, bbase + 16384 + dstA0);               \
    gload16(Ap + off1 + (kt) * GBK2, bbase + dstA1);                       \
    gload16(Bp + off1 + (kt) * GBK2, bbase + 16384 + dstA1);               \
  }

#define TILE(t, bb, VMS, DOSTG)                                            \
  {                                                                        \
    asm volatile("s_waitcnt vmcnt(" VMS ")" ::: "memory");                 \
    __builtin_amdgcn_s_barrier();                                          \
    if (DOSTG) STG((t) + 2, ((bb) + 2) & 3);                               \
    const char* buf = lds + (bb) * BUF2;                                   \
    bf16x8 af[8], bf[4];                                                   \
    _Pragma("unroll")                                                      \
    for (int mi = 0; mi < 8; ++mi) af[mi] = *(const bf16x8*)(buf + aro[mi]); \
    _Pragma("unroll")                                                      \
    for (int ni = 0; ni < 4; ++ni) bf[ni] = *(const bf16x8*)(buf + bro[ni]); \
    asm volatile("s_waitcnt lgkmcnt(0)" ::: "memory");                     \
    __builtin_amdgcn_sched_barrier(0);                                     \
    __builtin_amdgcn_s_setprio(1);                                         \
    _Pragma("unroll")                                                      \
    for (int mi = 0; mi < 8; ++mi)                                         \
      _Pragma("unroll")                                                    \
      for (int ni = 0; ni < 4; ++ni)                                       \
        acc[mi][ni] = __builtin_amdgcn_mfma_f32_16x16x32_bf16(af[mi], bf[ni], acc[mi][ni], 0, 0, 0); \
    __builtin_amdgcn_s_setprio(0);                                         \
  }

  STG(0, 0);
  STG(1, 1);
#pragma unroll 1
  for (int t4 = 0; t4 < 7; ++t4) {
    const int t = t4 * 4;
    TILE(t + 0, 0, "4", 1);
    TILE(t + 1, 1, "4", 1);
    TILE(t + 2, 2, "4", 1);
    TILE(t + 3, 3, "4", 1);
  }
  TILE(28, 0, "4", 1);
  TILE(29, 1, "4", 1);
  TILE(30, 2, "4", 0);
  TILE(31, 3, "0", 0);
#undef STG
#undef TILE

  // ---- epilogue: LDS transpose -> coalesced 16B stores ----
  __syncthreads();
  u16* tile = (u16*)lds;   // [256][256] bf16
#pragma unroll
  for (int mi = 0; mi < 8; ++mi)
#pragma unroll
    for (int ni = 0; ni < 4; ++ni)
#pragma unroll
      for (int jj = 0; jj < 4; ++jj) {
        int r = wm * 128 + mi * 16 + kg * 4 + jj;
        int ccol = wn * 64 + ni * 16 + lm;
        tile[r * 256 + ccol] = f2bf(acc[mi][ni][jj]);
      }
  __syncthreads();
#pragma unroll
  for (int it = 0; it < 8; ++it) {
    int r = it * 32 + (tid >> 4);
    int cb = (tid & 15) * 32;
    *(f32x4*)((char*)C + ((size_t)(bm * 256 + r) * NKV + bn * 256) * 2 + cb) =
        *(const f32x4*)((char*)tile + r * 512 + cb);
    *(f32x4*)((char*)C + ((size_t)(bm * 256 + r) * NKV + bn * 256) * 2 + cb + 16) =
        *(const f32x4*)((char*)tile + r * 512 + cb + 16);
  }
}

// ---------------- kernel 4: fused gate + v_g + rmsnorm + dilated conv + silu + add ----------------
#define CR 32   // rows per block

__global__ __launch_bounds__(256) void k_gateconv(
    const float* __restrict__ hidden, const u16* __restrict__ KV,
    const float* __restrict__ qw, const float* __restrict__ kw,
    const float* __restrict__ cw, const float* __restrict__ convw,
    const float* __restrict__ convb, float* __restrict__ out) {
  __shared__ float ring[10][1024];   // 40KB h history (f32)
  __shared__ float red[4][4];
  const int blk = blockIdx.x;
  const int b = blk >> 7;                 // 128 chunks per batch
  const int l0 = (blk & 127) * CR;
  const int tid = threadIdx.x;
  const int c = tid * 4;
  const int w = tid >> 6, ln = tid & 63;

  f32x4 qv = *(const f32x4*)&qw[c];
  f32x4 kv = *(const f32x4*)&kw[c];
  f32x4 cwv = *(const f32x4*)&cw[c];
  f32x4 cb = *(const f32x4*)&convb[c];
  f32x4 wt0 = *(const f32x4*)&convw[c * 4];
  f32x4 wt1 = *(const f32x4*)&convw[(c + 1) * 4];
  f32x4 wt2 = *(const f32x4*)&convw[(c + 2) * 4];
  f32x4 wt3 = *(const f32x4*)&convw[(c + 3) * 4];

  int slot = 0;
  f32x4 px = (f32x4){0.f, 0.f, 0.f, 0.f};
  u16x4 pk = (u16x4){0, 0, 0, 0}, pv = (u16x4){0, 0, 0, 0};
  if (l0 - 9 >= 0) {
    size_t m = (size_t)b * LL + (l0 - 9);
    px = *(const f32x4*)&hidden[m * HID + c];
    pk = *(const u16x4*)&KV[m * NKV + c];
    pv = *(const u16x4*)&KV[m * NKV + HID + c];
  }

  for (int r = l0 - 9; r < l0 + CR; ++r) {
    const bool live = (r >= 0);
    f32x4 x = px;
    u16x4 kk = pk, vvx = pv;
    if (r + 1 < l0 + CR && r + 1 >= 0) {
      size_t m2 = (size_t)b * LL + (r + 1);
      px = *(const f32x4*)&hidden[m2 * HID + c];
      pk = *(const u16x4*)&KV[m2 * NKV + c];
      pv = *(const u16x4*)&KV[m2 * NKV + HID + c];
    }
    float s0 = 0.f, s1 = 0.f, s2 = 0.f, s3 = 0.f;
    float kf[4], vf[4];
    if (live) {
#pragma unroll
      for (int i = 0; i < 4; ++i) {
        kf[i] = bf2f(kk[i]);
        vf[i] = bf2f(vvx[i]);
        s0 += x[i] * x[i];
        s1 += kf[i] * kf[i];
        s2 += (x[i] * qv[i]) * (kf[i] * kv[i]);
        s3 += vf[i] * vf[i];
      }
    }
#pragma unroll
    for (int mm = 32; mm >= 1; mm >>= 1) {
      s0 += __shfl_xor(s0, mm, 64);
      s1 += __shfl_xor(s1, mm, 64);
      s2 += __shfl_xor(s2, mm, 64);
      s3 += __shfl_xor(s3, mm, 64);
    }
    __syncthreads();
    if (ln == 0) { red[w][0] = s0; red[w][1] = s1; red[w][2] = s2; red[w][3] = s3; }
    __syncthreads();
    float t0 = red[0][0] + red[1][0] + red[2][0] + red[3][0];
    float t1 = red[0][1] + red[1][1] + red[2][1] + red[3][1];
    float t2 = red[0][2] + red[1][2] + red[2][2] + red[3][2];
    float t3 = red[0][3] + red[1][3] + red[2][3] + red[3][3];

    f32x4 vg = (f32x4){0.f, 0.f, 0.f, 0.f};
    float h[4] = {0.f, 0.f, 0.f, 0.f};
    if (live) {
      const float inv = 0.0009765625f;  // 1/1024
      float rq = rsqrtf(t0 * inv + EPSF);
      float rk = rsqrtf(t1 * inv + EPSF);
      float gate = 1.f / (1.f + expf(-rq * rk * t2 * 0.03125f));
      float rv = rsqrtf(gate * gate * t3 * inv + EPSF);
      float grv = gate * rv;
#pragma unroll
      for (int i = 0; i < 4; ++i) {
        vg[i] = gate * vf[i];
        h[i] = vf[i] * grv * cwv[i];
      }
    }
    *(f32x4*)&ring[slot][c] = (f32x4){h[0], h[1], h[2], h[3]};

    if (r >= l0) {
      int s9 = slot + 1; s9 = s9 >= 10 ? s9 - 10 : s9;   // row r-9
      int s6 = slot + 4; s6 = s6 >= 10 ? s6 - 10 : s6;   // row r-6
      int s3v = slot + 7; s3v = s3v >= 10 ? s3v - 10 : s3v; // row r-3
      f32x4 h9 = *(const f32x4*)&ring[s9][c];
      f32x4 h6 = *(const f32x4*)&ring[s6][c];
      f32x4 h3 = *(const f32x4*)&ring[s3v][c];
      f32x4 res;
#pragma unroll
      for (int i = 0; i < 4; ++i) {
        f32x4 wt = (i == 0) ? wt0 : (i == 1) ? wt1 : (i == 2) ? wt2 : wt3;
        float y = cb[i] + h9[i] * wt[0] + h6[i] * wt[1] + h3[i] * wt[2] + h[i] * wt[3];
        res[i] = y / (1.f + expf(-y)) + vg[i];
      }
      *(f32x4*)&out[((size_t)b * LL + r) * HID + c] = res;
    }
    slot = slot + 1 >= 10 ? 0 : slot + 1;
  }
}

// ---------------- launch ----------------
extern "C" void kernel_launch(void* const* d_in, const int* in_sizes, int n_in,
                              void* d_out, int out_size, void* d_ws, size_t ws_size,
                              hipStream_t stream) {
  const float* hidden   = (const float*)d_in[0];
  const int*   tok      = (const int*)d_in[1];
  const int*   proj     = (const int*)d_in[2];
  const int*   m2       = (const int*)d_in[3];
  const int*   m3       = (const int*)d_in[4];
  const int*   tsz      = (const int*)d_in[5];
  const float* tables   = (const float*)d_in[6];
  const float* wk       = (const float*)d_in[7];
  const float* wv       = (const float*)d_in[8];
  const float* qw       = (const float*)d_in[9];
  const float* kw       = (const float*)d_in[10];
  const float* cnw      = (const float*)d_in[11];
  const float* convw    = (const float*)d_in[12];
  const float* convb    = (const float*)d_in[13];
  float* out = (float*)d_out;

  const int max_s = in_sizes[6] / (2 * 8 * 64);

  char* ws = (char*)d_ws;
  u16* mem = (u16*)ws;                                     // 32 MB  bf16 memory[16384][1024]
  u16* W   = (u16*)(ws + (size_t)33554432);                //  4 MB  bf16 W[2048][1024]
  u16* KV  = (u16*)(ws + (size_t)33554432 + 4194304);      // 64 MB  bf16 kv[16384][2048]

  k_convert_w<<<dim3((NKV * KDIM / 4 + 255) / 256), dim3(256), 0, stream>>>(wk, wv, W);
  k_gather<<<dim3(MTOK), dim3(256), 0, stream>>>(tok, proj, m2, m3, tsz, tables, max_s, mem);
  k_gemm<<<dim3((MTOK / 256) * (NKV / 256)), dim3(512), 0, stream>>>(mem, W, KV);
  k_gateconv<<<dim3(BB * (LL / CR)), dim3(256), 0, stream>>>(hidden, KV, qw, kw, cnw, convw, convb, out);
}

// Round 4
// 160.495 us; speedup vs baseline: 1.3616x; 1.1360x over previous
//
#include <hip/hip_runtime.h>
#include <hip/hip_bf16.h>
#include <math.h>

typedef unsigned short u16;
typedef __bf16 bf16x8 __attribute__((ext_vector_type(8)));
typedef float f32x4 __attribute__((ext_vector_type(4)));
typedef unsigned short u16x4 __attribute__((ext_vector_type(4)));
typedef unsigned short u16x8 __attribute__((ext_vector_type(8)));

#define BB 4
#define LL 4096
#define MTOK (BB*LL)
#define HID 1024
#define NKV 2048
#define KDIM 1024
#define VOCABN 32000
#define EPSF 1e-6f

__device__ __forceinline__ float bf2f(u16 x) {
  unsigned u = ((unsigned)x) << 16;
  return __builtin_bit_cast(float, u);
}
__device__ __forceinline__ u16 f2bf(float f) {
  unsigned u = __builtin_bit_cast(unsigned, f);
  u += 0x7FFFu + ((u >> 16) & 1u);
  return (u16)(u >> 16);
}

// ---------------- kernel 1: convert w_k || w_v -> bf16 W[2048][1024] ----------------
__global__ __launch_bounds__(256) void k_convert_w(const float* __restrict__ wk,
                                                   const float* __restrict__ wv,
                                                   u16* __restrict__ W) {
  int i = blockIdx.x * 256 + threadIdx.x;
  const int n4 = (NKV * KDIM) / 4;
  if (i >= n4) return;
  const int half = n4 / 2;
  const f32x4* src = (i < half) ? (const f32x4*)wk : (const f32x4*)wv;
  int j = (i < half) ? i : i - half;
  f32x4 v = src[j];
  u16x4 o = { f2bf(v[0]), f2bf(v[1]), f2bf(v[2]), f2bf(v[3]) };
  *(u16x4*)&W[(size_t)i * 4] = o;
}

// ---------------- kernel 2: hash + gather -> bf16 memory[16384][1024] ----------------
__global__ __launch_bounds__(256) void k_gather(
    const int* __restrict__ tok, const int* __restrict__ proj,
    const int* __restrict__ m2, const int* __restrict__ m3,
    const int* __restrict__ tsz, const float* __restrict__ tables,
    int max_s, u16* __restrict__ mem) {
  int m = blockIdx.x;
  int l = m & (LL - 1);
  int tid = threadIdx.x;
  int t = tid >> 4;
  int q = tid & 15;
  long long c0, c1 = 0, c2 = 0;
  {
    int tk = tok[m];
    tk = tk < 0 ? 0 : (tk > VOCABN - 1 ? VOCABN - 1 : tk);
    c0 = proj[tk];
  }
  if (l >= 1) {
    int tk = tok[m - 1];
    tk = tk < 0 ? 0 : (tk > VOCABN - 1 ? VOCABN - 1 : tk);
    c1 = proj[tk];
  }
  if (l >= 2) {
    int tk = tok[m - 2];
    tk = tk < 0 ? 0 : (tk > VOCABN - 1 ? VOCABN - 1 : tk);
    c2 = proj[tk];
  }
  int order = t >> 3, h = t & 7;
  long long mix;
  if (order == 0) {
    mix = (c1 * (long long)m2[h * 2 + 0]) ^ (c0 * (long long)m2[h * 2 + 1]);
  } else {
    mix = (c2 * (long long)m3[h * 3 + 0]) ^ (c1 * (long long)m3[h * 3 + 1]) ^
          (c0 * (long long)m3[h * 3 + 2]);
  }
  unsigned long long um = (unsigned long long)(mix < 0 ? -mix : mix);
  unsigned long long usz = (unsigned long long)tsz[t];
  unsigned long long qq = (unsigned long long)((double)um / (double)usz);
  long long r = (long long)(um - qq * usz);
  if (r < 0) r += (long long)usz;
  else if (r >= (long long)usz) r -= (long long)usz;
  const f32x4* src = (const f32x4*)(tables + ((size_t)t * (size_t)max_s + (size_t)r) * 64);
  f32x4 e = src[q];
  u16x4 o = { f2bf(e[0]), f2bf(e[1]), f2bf(e[2]), f2bf(e[3]) };
  *(u16x4*)&mem[(size_t)m * HID + t * 64 + q * 4] = o;
}

// ---------------- kernel 3: 256x256 GEMM, BK=32, 4-buffer 3-deep pipeline ----------------
#define GBK2 32
#define BUF2 32768

__device__ __forceinline__ void gload16(const void* g, void* l) {
  __builtin_amdgcn_global_load_lds((__attribute__((address_space(1))) void*)(g),
                                   (__attribute__((address_space(3))) void*)(l), 16, 0, 0);
}
__device__ __forceinline__ int swz32(int x) { return x ^ (((x >> 6) & 3) << 4); }

__global__ __launch_bounds__(512, 2) void k_gemm(const u16* __restrict__ A,
                                                 const u16* __restrict__ Bw,
                                                 u16* __restrict__ C) {
  __shared__ __align__(16) char lds[131072];
  const int d = blockIdx.x;
  const int wg = (d & 7) * 64 + (d >> 3);     // XCD-bijective (512 % 8 == 0)
  const int bm = wg >> 3, bn = wg & 7;
  const int tid = threadIdx.x;
  const int w = tid >> 6, lane = tid & 63;
  const int wm = w >> 2, wn = w & 3;
  const int lm = lane & 15, kg = lane >> 4;

  const int ca0 = w * 2, ca1 = w * 2 + 1;
  const int row0 = ca0 * 16 + (lane >> 2);
  const int row1 = ca1 * 16 + (lane >> 2);
  const int off0 = row0 * KDIM + (((lane & 3) ^ (row0 & 3)) << 3);
  const int off1 = row1 * KDIM + (((lane & 3) ^ (row1 & 3)) << 3);
  const int dstA0 = ca0 * 1024 + lane * 16;
  const int dstA1 = ca1 * 1024 + lane * 16;
  const u16* Ap = A + (size_t)bm * 256 * KDIM;
  const u16* Bp = Bw + (size_t)bn * 256 * KDIM;

  int aro[8], bro[4];
#pragma unroll
  for (int mi = 0; mi < 8; ++mi)
    aro[mi] = swz32((wm * 128 + mi * 16 + lm) * 64 + kg * 16);
#pragma unroll
  for (int ni = 0; ni < 4; ++ni)
    bro[ni] = 16384 + swz32((wn * 64 + ni * 16 + lm) * 64 + kg * 16);

  f32x4 acc[8][4];
#pragma unroll
  for (int i = 0; i < 8; ++i)
#pragma unroll
    for (int j = 0; j < 4; ++j) acc[i][j] = (f32x4){0.f, 0.f, 0.f, 0.f};

#define STG(kt, bb)                                                        \
  {                                                                        \
    char* bbase = lds + (bb) * BUF2;                                       \
    gload16(Ap + off0 + (kt) * GBK2, bbase + dstA0);                       \
    gload16(Bp + off0 + (kt) * GBK2, bbase + 16384 + dstA0);               \
    gload16(Ap + off1 + (kt) * GBK2, bbase + dstA1);                       \
    gload16(Bp + off1 + (kt) * GBK2, bbase + 16384 + dstA1);               \
  }

#define TILE(t, bb, VMS, DOSTG)                                            \
  {                                                                        \
    asm volatile("s_waitcnt vmcnt(" VMS ")" ::: "memory");                 \
    __builtin_amdgcn_s_barrier();                                          \
    if (DOSTG) STG((t) + 3, ((bb) + 3) & 3);                               \
    const char* buf = lds + (bb) * BUF2;                                   \
    bf16x8 af[8], bf[4];                                                   \
    _Pragma("unroll")                                                      \
    for (int mi = 0; mi < 8; ++mi) af[mi] = *(const bf16x8*)(buf + aro[mi]); \
    _Pragma("unroll")                                                      \
    for (int ni = 0; ni < 4; ++ni) bf[ni] = *(const bf16x8*)(buf + bro[ni]); \
    asm volatile("s_waitcnt lgkmcnt(0)" ::: "memory");                     \
    __builtin_amdgcn_sched_barrier(0);                                     \
    __builtin_amdgcn_s_setprio(1);                                         \
    _Pragma("unroll")                                                      \
    for (int mi = 0; mi < 8; ++mi)                                         \
      _Pragma("unroll")                                                    \
      for (int ni = 0; ni < 4; ++ni)                                       \
        acc[mi][ni] = __builtin_amdgcn_mfma_f32_16x16x32_bf16(af[mi], bf[ni], acc[mi][ni], 0, 0, 0); \
    __builtin_amdgcn_s_setprio(0);                                         \
  }

  STG(0, 0);
  STG(1, 1);
  STG(2, 2);
#pragma unroll 1
  for (int t4 = 0; t4 < 7; ++t4) {
    const int t = t4 * 4;
    TILE(t + 0, 0, "8", 1);
    TILE(t + 1, 1, "8", 1);
    TILE(t + 2, 2, "8", 1);
    TILE(t + 3, 3, "8", 1);
  }
  TILE(28, 0, "8", 1);   // stages tile 31
  TILE(29, 1, "8", 0);
  TILE(30, 2, "4", 0);
  TILE(31, 3, "0", 0);
#undef STG
#undef TILE

  // ---- epilogue: LDS transpose -> coalesced 16B stores ----
  __syncthreads();
  u16* tile = (u16*)lds;
#pragma unroll
  for (int mi = 0; mi < 8; ++mi)
#pragma unroll
    for (int ni = 0; ni < 4; ++ni)
#pragma unroll
      for (int jj = 0; jj < 4; ++jj) {
        int r = wm * 128 + mi * 16 + kg * 4 + jj;
        int ccol = wn * 64 + ni * 16 + lm;
        tile[r * 256 + ccol] = f2bf(acc[mi][ni][jj]);
      }
  __syncthreads();
#pragma unroll
  for (int it = 0; it < 8; ++it) {
    int r = it * 32 + (tid >> 4);
    int cb = (tid & 15) * 32;
    *(f32x4*)((char*)C + ((size_t)(bm * 256 + r) * NKV + bn * 256) * 2 + cb) =
        *(const f32x4*)((char*)tile + r * 512 + cb);
    *(f32x4*)((char*)C + ((size_t)(bm * 256 + r) * NKV + bn * 256) * 2 + cb + 16) =
        *(const f32x4*)((char*)tile + r * 512 + cb + 16);
  }
}

// ---------------- kernel 4: fused gate+conv, wave-per-row ----------------
#define CR 32

__global__ __launch_bounds__(256, 2) void k_gateconv(
    const float* __restrict__ hidden, const u16* __restrict__ KV,
    const float* __restrict__ qw, const float* __restrict__ kw,
    const float* __restrict__ cw, const float* __restrict__ convw,
    const float* __restrict__ convb, float* __restrict__ out) {
  __shared__ u16 ring[32][1024];   // 64KB bf16 h-history, slot = row & 31
  const int blk = blockIdx.x;
  const int b = blk >> 7;
  const int l0 = (blk & 127) * CR;
  const int w = threadIdx.x >> 6, ln = threadIdx.x & 63;
  // lane owns cols c = seg*512 + ln*8 + e, seg=0..1, e=0..7

  // ---- persistent per-lane weights ----
  float qk[16], cwv[16];
  f32x4 wt[16];
  f32x4 cbv[4];
#pragma unroll
  for (int seg = 0; seg < 2; ++seg) {
    int c0 = seg * 512 + ln * 8;
    f32x4 qa = *(const f32x4*)&qw[c0], qb = *(const f32x4*)&qw[c0 + 4];
    f32x4 ka = *(const f32x4*)&kw[c0], kb = *(const f32x4*)&kw[c0 + 4];
    f32x4 ca = *(const f32x4*)&cw[c0], cbx = *(const f32x4*)&cw[c0 + 4];
#pragma unroll
    for (int i = 0; i < 4; ++i) {
      qk[seg * 8 + i] = qa[i] * ka[i];
      qk[seg * 8 + 4 + i] = qb[i] * kb[i];
      cwv[seg * 8 + i] = ca[i];
      cwv[seg * 8 + 4 + i] = cbx[i];
    }
    cbv[seg * 2] = *(const f32x4*)&convb[c0];
    cbv[seg * 2 + 1] = *(const f32x4*)&convb[c0 + 4];
#pragma unroll
    for (int e = 0; e < 8; ++e) wt[seg * 8 + e] = *(const f32x4*)&convw[(c0 + e) * 4];
  }

  const int base = l0 - 12;
  // row buffers (cur / next)
  f32x4 x0, x1, x2, x3, nx0, nx1, nx2, nx3;
  u16x8 kk0, kk1, vv0, vv1, nk0, nk1, nv0, nv1;

#define LOADROW(r, X0, X1, X2, X3, K0, K1, V0, V1)                             \
  {                                                                            \
    X0 = (f32x4){0.f,0.f,0.f,0.f}; X1 = X0; X2 = X0; X3 = X0;                  \
    K0 = (u16x8){0,0,0,0,0,0,0,0}; K1 = K0; V0 = K0; V1 = K0;                  \
    if ((r) >= l0 - 9 && (r) >= 0) {                                           \
      size_t mr = (size_t)b * LL + (r);                                        \
      X0 = *(const f32x4*)&hidden[mr * HID + ln * 8];                          \
      X1 = *(const f32x4*)&hidden[mr * HID + ln * 8 + 4];                      \
      X2 = *(const f32x4*)&hidden[mr * HID + 512 + ln * 8];                    \
      X3 = *(const f32x4*)&hidden[mr * HID + 512 + ln * 8 + 4];                \
      K0 = *(const u16x8*)&KV[mr * NKV + ln * 8];                              \
      K1 = *(const u16x8*)&KV[mr * NKV + 512 + ln * 8];                        \
      V0 = *(const u16x8*)&KV[mr * NKV + HID + ln * 8];                        \
      V1 = *(const u16x8*)&KV[mr * NKV + HID + 512 + ln * 8];                  \
    }                                                                          \
  }

  LOADROW(base + w, x0, x1, x2, x3, kk0, kk1, vv0, vv1);

#pragma unroll 1
  for (int g = 0; g < 11; ++g) {
    const int r = base + g * 4 + w;
    if (g < 10) {
      LOADROW(r + 4, nx0, nx1, nx2, nx3, nk0, nk1, nv0, nv1);
    }
    // ---- per-lane partial sums ----
    float s0 = 0.f, s1 = 0.f, s2 = 0.f, s3 = 0.f;
#pragma unroll
    for (int e = 0; e < 8; ++e) {
      float xa = (e < 4) ? x0[e] : x1[e - 4];
      float xb = (e < 4) ? x2[e] : x3[e - 4];
      float ka = bf2f(kk0[e]), kb = bf2f(kk1[e]);
      float va = bf2f(vv0[e]), vb = bf2f(vv1[e]);
      s0 += xa * xa + xb * xb;
      s1 += ka * ka + kb * kb;
      s2 += xa * qk[e] * ka + xb * qk[8 + e] * kb;
      s3 += va * va + vb * vb;
    }
#pragma unroll
    for (int mm = 32; mm >= 1; mm >>= 1) {
      s0 += __shfl_xor(s0, mm, 64);
      s1 += __shfl_xor(s1, mm, 64);
      s2 += __shfl_xor(s2, mm, 64);
      s3 += __shfl_xor(s3, mm, 64);
    }
    const float inv = 0.0009765625f;
    float rq = rsqrtf(s0 * inv + EPSF);
    float rk = rsqrtf(s1 * inv + EPSF);
    float gate = 1.f / (1.f + expf(-rq * rk * s2 * 0.03125f));
    float rv = rsqrtf(gate * gate * s3 * inv + EPSF);
    float grv = gate * rv;

    u16x8 h0p, h1p;
#pragma unroll
    for (int e = 0; e < 8; ++e) {
      h0p[e] = f2bf(bf2f(vv0[e]) * grv * cwv[e]);
      h1p[e] = f2bf(bf2f(vv1[e]) * grv * cwv[8 + e]);
    }
    const int slot = r & 31;
    *(u16x8*)&ring[slot][ln * 8] = h0p;
    *(u16x8*)&ring[slot][512 + ln * 8] = h1p;
    __syncthreads();

    if (r >= l0) {
      const int s9 = (r - 9) & 31, s6 = (r - 6) & 31, s3s = (r - 3) & 31;
      size_t mr = (size_t)b * LL + r;
#pragma unroll
      for (int seg = 0; seg < 2; ++seg) {
        u16x8 a9 = *(const u16x8*)&ring[s9][seg * 512 + ln * 8];
        u16x8 a6 = *(const u16x8*)&ring[s6][seg * 512 + ln * 8];
        u16x8 a3 = *(const u16x8*)&ring[s3s][seg * 512 + ln * 8];
        const u16x8 vv = seg ? vv1 : vv0;
        f32x4 ra, rb;
#pragma unroll
        for (int e = 0; e < 8; ++e) {
          const int idx = seg * 8 + e;
          float vf = bf2f(vv[e]);
          float hown = vf * grv * cwv[idx];
          f32x4 wv = wt[idx];
          float y = cbv[seg * 2 + (e >> 2)][e & 3] + bf2f(a9[e]) * wv[0] +
                    bf2f(a6[e]) * wv[1] + bf2f(a3[e]) * wv[2] + hown * wv[3];
          float res = y / (1.f + expf(-y)) + gate * vf;
          if (e < 4) ra[e] = res; else rb[e - 4] = res;
        }
        *(f32x4*)&out[mr * HID + seg * 512 + ln * 8] = ra;
        *(f32x4*)&out[mr * HID + seg * 512 + ln * 8 + 4] = rb;
      }
    }
    // rotate buffers
    x0 = nx0; x1 = nx1; x2 = nx2; x3 = nx3;
    kk0 = nk0; kk1 = nk1; vv0 = nv0; vv1 = nv1;
  }
#undef LOADROW
}

// ---------------- launch ----------------
extern "C" void kernel_launch(void* const* d_in, const int* in_sizes, int n_in,
                              void* d_out, int out_size, void* d_ws, size_t ws_size,
                              hipStream_t stream) {
  const float* hidden   = (const float*)d_in[0];
  const int*   tok      = (const int*)d_in[1];
  const int*   proj     = (const int*)d_in[2];
  const int*   m2       = (const int*)d_in[3];
  const int*   m3       = (const int*)d_in[4];
  const int*   tsz      = (const int*)d_in[5];
  const float* tables   = (const float*)d_in[6];
  const float* wk       = (const float*)d_in[7];
  const float* wv       = (const float*)d_in[8];
  const float* qw       = (const float*)d_in[9];
  const float* kw       = (const float*)d_in[10];
  const float* cnw      = (const float*)d_in[11];
  const float* convw    = (const float*)d_in[12];
  const float* convb    = (const float*)d_in[13];
  float* out = (float*)d_out;

  const int max_s = in_sizes[6] / (2 * 8 * 64);

  char* ws = (char*)d_ws;
  u16* mem = (u16*)ws;                                     // 32 MB  bf16 memory[16384][1024]
  u16* W   = (u16*)(ws + (size_t)33554432);                //  4 MB  bf16 W[2048][1024]
  u16* KV  = (u16*)(ws + (size_t)33554432 + 4194304);      // 64 MB  bf16 kv[16384][2048]

  k_convert_w<<<dim3((NKV * KDIM / 4 + 255) / 256), dim3(256), 0, stream>>>(wk, wv, W);
  k_gather<<<dim3(MTOK), dim3(256), 0, stream>>>(tok, proj, m2, m3, tsz, tables, max_s, mem);
  k_gemm<<<dim3((MTOK / 256) * (NKV / 256)), dim3(512), 0, stream>>>(mem, W, KV);
  k_gateconv<<<dim3(BB * (LL / CR)), dim3(256), 0, stream>>>(hidden, KV, qw, kw, cnw, convw, convb, out);
}